// Round 4
// baseline (387.809 us; speedup 1.0000x reference)
//
#include <hip/hip_runtime.h>
#include <math.h>

#define V 32000
#define E 512
#define H 512
#define N 64
#define L 128
#define NV (N*V)
#define NH (N*H)
#define MTOT (N*L)   // 8192 rows of the score GEMM
#define VT 1000      // v-tiles (of 32) in k_logits

typedef short  s8v  __attribute__((ext_vector_type(8)));   // 8 bf16 (4 VGPRs)
typedef float  f4v  __attribute__((ext_vector_type(4)));

__device__ __forceinline__ float sigf(float x) { return 1.0f / (1.0f + __expf(-x)); }

// fp32 -> bf16 round-to-nearest-even
__device__ __forceinline__ unsigned short f2bf(float f) {
    unsigned int u = __float_as_uint(f);
    unsigned int r = u + 0x7FFFu + ((u >> 16) & 1u);
    return (unsigned short)(r >> 16);
}
__device__ __forceinline__ float bf2f(unsigned short u) {
    return __uint_as_float(((unsigned int)u) << 16);
}

// ---------------------------------------------------------------------------
// K0: convert enc (fp32, N*L*H) and Ws (fp32, H*H) to bf16 once.
// 8 elements per thread. grid 2176 x 256.
// ---------------------------------------------------------------------------
__global__ __launch_bounds__(256) void k_prep(
    const float* __restrict__ enc, const float* __restrict__ Ws,
    unsigned short* __restrict__ encb, unsigned short* __restrict__ Wsb)
{
    size_t g = (size_t)blockIdx.x * 256 + threadIdx.x;  // group of 8 elements
    const float* src;
    unsigned short* dst;
    size_t off;
    if (g < (size_t)N * L * H / 8) { src = enc; dst = encb; off = g * 8; }
    else { src = Ws; dst = Wsb; off = (g - (size_t)N * L * H / 8) * 8; }
    float4 a = ((const float4*)(src + off))[0];
    float4 b = ((const float4*)(src + off))[1];
    union { unsigned short u[8]; uint4 q; } p;
    p.u[0]=f2bf(a.x); p.u[1]=f2bf(a.y); p.u[2]=f2bf(a.z); p.u[3]=f2bf(a.w);
    p.u[4]=f2bf(b.x); p.u[5]=f2bf(b.y); p.u[6]=f2bf(b.z); p.u[7]=f2bf(b.w);
    *(uint4*)(dst + off) = p.q;
}

// ---------------------------------------------------------------------------
// K1: LSTM gate GEMM, k-split partials. grid (32 j-tiles, 8 k-splits of 128),
// block 256 = 64 j-lanes x 4 n-groups(16 n). LDS 32 KB.
// ---------------------------------------------------------------------------
__global__ __launch_bounds__(256) void k_gates(
    const int* __restrict__ ids, const float* __restrict__ hprev,
    const float* __restrict__ embW, const float* __restrict__ w_ih,
    const float* __restrict__ w_hh, float* __restrict__ gates_p)
{
    __shared__ __align__(16) float xs[64 * 128];  // 32 KB
    const int bx = blockIdx.x;   // j-tile
    const int ks = blockIdx.y;   // k-split (0..7): 0-3 emb, 4-7 h
    const int tid = threadIdx.x;
    const bool emb_part = (ks < 4);
    const int koff = (ks & 3) * 128;

    for (int i = tid; i < 64 * 32; i += 256) {
        int n = i >> 5, kk4 = i & 31;
        float4 x4;
        if (emb_part)
            x4 = ((const float4*)(embW + (size_t)ids[n] * E + koff))[kk4];
        else
            x4 = ((const float4*)(hprev + (size_t)n * H + koff))[kk4];
        ((float4*)xs)[n * 32 + kk4] = x4;
    }
    __syncthreads();

    const int jl = tid & 63;
    const int ng = tid >> 6;
    const int j = bx * 64 + jl;
    const int nb = ng * 16;
    const float* wrow = (emb_part ? w_ih : w_hh) + (size_t)j * 512 + koff;

    float acc[16];
#pragma unroll
    for (int i = 0; i < 16; ++i) acc[i] = 0.f;

    for (int e4 = 0; e4 < 32; ++e4) {
        float4 w4 = ((const float4*)wrow)[e4];
#pragma unroll
        for (int i = 0; i < 16; ++i) {
            float4 x4 = ((const float4*)xs)[(nb + i) * 32 + e4];  // wave-uniform broadcast
            acc[i] += w4.x * x4.x + w4.y * x4.y + w4.z * x4.z + w4.w * x4.w;
        }
    }
#pragma unroll
    for (int i = 0; i < 16; ++i)
        gates_p[(size_t)ks * (64 * 2048) + (size_t)(nb + i) * 2048 + j] = acc[i];
}

// ---------------------------------------------------------------------------
// K1b: combine partials + biases, LSTM pointwise. Writes h_t, c_t into d_out
// and bf16 h_t into xb[:, 0:512].
// ---------------------------------------------------------------------------
__global__ __launch_bounds__(256) void k_lstm_pw(
    const float* __restrict__ gates_p, const float* __restrict__ b_ih,
    const float* __restrict__ b_hh, const float* __restrict__ cprev,
    float* __restrict__ out, unsigned short* __restrict__ xb)
{
    int i = blockIdx.x * 256 + threadIdx.x;  // 0..32767
    if (i >= NH) return;
    int n = i >> 9, k = i & 511;
    float g[4];
#pragma unroll
    for (int q = 0; q < 4; ++q) {
        int j = q * 512 + k;
        float s = b_ih[j] + b_hh[j];
#pragma unroll
        for (int ks = 0; ks < 8; ++ks)
            s += gates_p[(size_t)ks * (64 * 2048) + (size_t)n * 2048 + j];
        g[q] = s;
    }
    float ig = sigf(g[0]), fg = sigf(g[1]), gg = tanhf(g[2]), og = sigf(g[3]);
    float ct = fg * cprev[i] + ig * gg;
    float ht = og * tanhf(ct);
    out[NV + i] = ht;
    out[NV + NH + i] = ct;
    xb[(size_t)n * 1024 + k] = f2bf(ht);
}

// ---------------------------------------------------------------------------
// K2a: sproj = h_t @ Wh.T  (64 x 512, K=512). grid 128, block 256.
// ---------------------------------------------------------------------------
__global__ __launch_bounds__(256) void k_sproj(
    const float* __restrict__ out, const float* __restrict__ Wh,
    float* __restrict__ sproj)
{
    __shared__ __align__(16) float xs[512];
    int n = blockIdx.x >> 1;
    int h = (blockIdx.x & 1) * 256 + threadIdx.x;
    const float* ht = out + NV + (size_t)n * 512;
    for (int i = threadIdx.x; i < 512; i += 256) xs[i] = ht[i];
    __syncthreads();
    const float* wrow = Wh + (size_t)h * 512;
    float acc = 0.f;
    for (int e4 = 0; e4 < 128; ++e4) {
        float4 w4 = ((const float4*)wrow)[e4];
        float4 x4 = ((const float4*)xs)[e4];
        acc += w4.x * x4.x + w4.y * x4.y + w4.z * x4.z + w4.w * x4.w;
    }
    sproj[(size_t)n * 512 + h] = acc;
}

// ---------------------------------------------------------------------------
// K2b: score GEMM via bf16 MFMA, bf16 inputs (encb/Wsb from k_prep),
// register-prefetch staging (no in-loop conversion). grid (128,8), block 256.
// ---------------------------------------------------------------------------
__global__ __launch_bounds__(256) void k_score_gemm(
    const unsigned short* __restrict__ encb, const unsigned short* __restrict__ Wsb,
    const float* __restrict__ sproj, const float* __restrict__ av,
    float* __restrict__ scorep)
{
    __shared__ __align__(16) short As[64 * 72];
    __shared__ __align__(16) short Bs[64 * 72];
    __shared__ float sred[64];

    const int bm = blockIdx.x, bh = blockIdx.y;
    const int tid = threadIdx.x;
    const int w = tid >> 6, l = tid & 63;
    const int wave_m = (w >> 1) * 32, wave_h = (w & 1) * 32;
    const int lq = l >> 4, lr = l & 15;

    const int arow = tid >> 2;          // 0..63
    const int acol = (tid & 3) * 16;    // 0,16,32,48 (shorts)
    const unsigned short* aptr = encb + (size_t)(bm * 64 + arow) * 512 + acol;
    const unsigned short* bptr = Wsb  + (size_t)(bh * 64 + arow) * 512 + acol;

    if (tid < 64) sred[tid] = 0.f;

    f4v acc[2][2];
#pragma unroll
    for (int i = 0; i < 2; ++i)
#pragma unroll
        for (int j = 0; j < 2; ++j) acc[i][j] = (f4v)0.f;

    uint4 ra[2], rb[2];
    ra[0] = ((const uint4*)aptr)[0]; ra[1] = ((const uint4*)aptr)[1];
    rb[0] = ((const uint4*)bptr)[0]; rb[1] = ((const uint4*)bptr)[1];

#pragma unroll 1
    for (int kt = 0; kt < 8; ++kt) {
        if (kt) __syncthreads();
        *(uint4*)(As + arow * 72 + acol)     = ra[0];
        *(uint4*)(As + arow * 72 + acol + 8) = ra[1];
        *(uint4*)(Bs + arow * 72 + acol)     = rb[0];
        *(uint4*)(Bs + arow * 72 + acol + 8) = rb[1];
        __syncthreads();

        if (kt < 7) {
            const unsigned short* ap = aptr + (kt + 1) * 64;
            const unsigned short* bp = bptr + (kt + 1) * 64;
            ra[0] = ((const uint4*)ap)[0]; ra[1] = ((const uint4*)ap)[1];
            rb[0] = ((const uint4*)bp)[0]; rb[1] = ((const uint4*)bp)[1];
        }

#pragma unroll
        for (int ks = 0; ks < 2; ++ks) {
            s8v a_frag[2], b_frag[2];
#pragma unroll
            for (int i = 0; i < 2; ++i)
                a_frag[i] = *(const s8v*)(As + (wave_m + 16 * i + lr) * 72 + ks * 32 + lq * 8);
#pragma unroll
            for (int j = 0; j < 2; ++j)
                b_frag[j] = *(const s8v*)(Bs + (wave_h + 16 * j + lr) * 72 + ks * 32 + lq * 8);
#pragma unroll
            for (int i = 0; i < 2; ++i)
#pragma unroll
                for (int j = 0; j < 2; ++j)
                    acc[i][j] = __builtin_amdgcn_mfma_f32_16x16x32_bf16(
                        a_frag[i], b_frag[j], acc[i][j], 0, 0, 0);
        }
    }
    __syncthreads();

    const int hc0 = bh * 64 + wave_h + lr;
#pragma unroll
    for (int i = 0; i < 2; ++i) {
#pragma unroll
        for (int reg = 0; reg < 4; ++reg) {
            int m_local = wave_m + 16 * i + lq * 4 + reg;
            int m = bm * 64 + m_local;
            int n = m >> 7;
            float p = 0.f;
#pragma unroll
            for (int j = 0; j < 2; ++j) {
                int hc = hc0 + 16 * j;
                float val = acc[i][j][reg] + sproj[(size_t)n * 512 + hc];
                p += tanhf(val) * av[hc];
            }
            p += __shfl_xor(p, 1, 64);
            p += __shfl_xor(p, 2, 64);
            p += __shfl_xor(p, 4, 64);
            p += __shfl_xor(p, 8, 64);
            if (lr == 0) atomicAdd(&sred[m_local], p);
        }
    }
    __syncthreads();
    if (tid < 64)
        scorep[(size_t)bh * MTOT + bm * 64 + tid] = sred[tid];
}

// ---------------------------------------------------------------------------
// K2c: combine score partials, mask, softmax over L, context from bf16 enc;
// writes bf16 context into xb[:, 512:1024]. grid 64 (n), block 512.
// ---------------------------------------------------------------------------
__global__ __launch_bounds__(512) void k_softmax_ctx(
    const float* __restrict__ scorep, const unsigned char* __restrict__ mask,
    const unsigned short* __restrict__ encb, unsigned short* __restrict__ xb)
{
    __shared__ float sc[128];
    __shared__ float wl[128];
    const int n = blockIdx.x, t = threadIdx.x;

    if (t < 128) {
        float s = 0.f;
#pragma unroll
        for (int q = 0; q < 8; ++q)
            s += scorep[(size_t)q * MTOT + n * 128 + t];
        if (mask[(size_t)n * 128 + t]) s = -1e30f;
        sc[t] = s;
    }
    __syncthreads();
    if (t < 64) {
        float m = fmaxf(sc[t], sc[t + 64]);
#pragma unroll
        for (int off = 32; off > 0; off >>= 1) m = fmaxf(m, __shfl_xor(m, off, 64));
        float e0 = __expf(sc[t] - m), e1 = __expf(sc[t + 64] - m);
        float ss = e0 + e1;
#pragma unroll
        for (int off = 32; off > 0; off >>= 1) ss += __shfl_xor(ss, off, 64);
        float inv = 1.0f / ss;
        wl[t] = e0 * inv;
        wl[t + 64] = e1 * inv;
    }
    __syncthreads();

    const unsigned short* encn = encb + (size_t)n * L * H + t;
    float acc = 0.f;
#pragma unroll 4
    for (int ll = 0; ll < 128; ++ll)
        acc += wl[ll] * bf2f(encn[(size_t)ll * 512]);
    xb[(size_t)n * 1024 + 512 + t] = f2bf(acc);
}

// ---------------------------------------------------------------------------
// K4a: logits GEMM via bf16 MFMA, C^T view: M=v(32000), N=n(64), K=1024.
// grid 1000 (v-tiles of 32), block 128 = 2 waves. BK=64, 16 K-steps.
// LDS 13.8 KB (epilogue transpose buffer unioned over As/Bs) -> 4+ blocks/CU
// of independent barrier domains. Weights fp32->bf16 in regs with prefetch.
// ---------------------------------------------------------------------------
__global__ __launch_bounds__(128) void k_logits(
    const float* __restrict__ h2oW, const unsigned short* __restrict__ xb,
    const float* __restrict__ h2ob, float* __restrict__ dlogits,
    float* __restrict__ pmax, float* __restrict__ psum)
{
    __shared__ __align__(16) char smem[32 * 72 * 2 + 64 * 72 * 2];  // 13824 B
    short* As = (short*)smem;                 // 32 x 72 (v x k)
    short* Bs = (short*)(smem + 32 * 72 * 2); // 64 x 72 (n x k)
    float* cs = (float*)smem;                 // 64 x 36 (n x v), post-loop union

    const int bm = blockIdx.x;   // v-tile of 32
    const int tid = threadIdx.x;
    const int w = tid >> 6, l = tid & 63;
    const int wave_n = w * 32;
    const int lq = l >> 4, lr = l & 15;

    const int arow = tid >> 2;            // 0..31
    const int acol = (tid & 3) * 16;      // 0,16,32,48 (elements)
    const int brow = tid >> 1;            // 0..63
    const int bcol = (tid & 1) * 32;      // 0,32 (shorts)
    const float* aptr = h2oW + (size_t)(bm * 32 + arow) * 1024 + acol;
    const unsigned short* bptr = xb + (size_t)brow * 1024 + bcol;

    f4v acc[2][2];
#pragma unroll
    for (int i = 0; i < 2; ++i)
#pragma unroll
        for (int j = 0; j < 2; ++j) acc[i][j] = (f4v)0.f;

    float4 ra[4];
    uint4  rb[4];
#pragma unroll
    for (int r = 0; r < 4; ++r) ra[r] = ((const float4*)aptr)[r];
#pragma unroll
    for (int r = 0; r < 4; ++r) rb[r] = ((const uint4*)bptr)[r];

#pragma unroll 1
    for (int kt = 0; kt < 16; ++kt) {
        if (kt) __syncthreads();
        union { unsigned short u[8]; uint4 q; } p0, p1;
        p0.u[0]=f2bf(ra[0].x); p0.u[1]=f2bf(ra[0].y); p0.u[2]=f2bf(ra[0].z); p0.u[3]=f2bf(ra[0].w);
        p0.u[4]=f2bf(ra[1].x); p0.u[5]=f2bf(ra[1].y); p0.u[6]=f2bf(ra[1].z); p0.u[7]=f2bf(ra[1].w);
        p1.u[0]=f2bf(ra[2].x); p1.u[1]=f2bf(ra[2].y); p1.u[2]=f2bf(ra[2].z); p1.u[3]=f2bf(ra[2].w);
        p1.u[4]=f2bf(ra[3].x); p1.u[5]=f2bf(ra[3].y); p1.u[6]=f2bf(ra[3].z); p1.u[7]=f2bf(ra[3].w);
        *(uint4*)(As + arow * 72 + acol)     = p0.q;
        *(uint4*)(As + arow * 72 + acol + 8) = p1.q;
#pragma unroll
        for (int r = 0; r < 4; ++r)
            *(uint4*)(Bs + brow * 72 + bcol + 8 * r) = rb[r];
        __syncthreads();

        if (kt < 15) {
            const float* ap = aptr + (kt + 1) * 64;
            const unsigned short* bp = bptr + (kt + 1) * 64;
#pragma unroll
            for (int r = 0; r < 4; ++r) ra[r] = ((const float4*)ap)[r];
#pragma unroll
            for (int r = 0; r < 4; ++r) rb[r] = ((const uint4*)bp)[r];
        }

#pragma unroll
        for (int ks = 0; ks < 2; ++ks) {
            s8v a_frag[2], b_frag[2];
#pragma unroll
            for (int i = 0; i < 2; ++i)
                a_frag[i] = *(const s8v*)(As + (16 * i + lr) * 72 + ks * 32 + lq * 8);
#pragma unroll
            for (int j = 0; j < 2; ++j)
                b_frag[j] = *(const s8v*)(Bs + (wave_n + 16 * j + lr) * 72 + ks * 32 + lq * 8);
#pragma unroll
            for (int i = 0; i < 2; ++i)
#pragma unroll
                for (int j = 0; j < 2; ++j)
                    acc[i][j] = __builtin_amdgcn_mfma_f32_16x16x32_bf16(
                        a_frag[i], b_frag[j], acc[i][j], 0, 0, 0);
        }
    }
    __syncthreads();

    // transpose through LDS union: cs[n_local][v_local], stride 36
#pragma unroll
    for (int i = 0; i < 2; ++i)
#pragma unroll
        for (int j = 0; j < 2; ++j)
#pragma unroll
            for (int reg = 0; reg < 4; ++reg)
                cs[(wave_n + 16 * j + lr) * 36 + 16 * i + lq * 4 + reg] = acc[i][j][reg];
    __syncthreads();

    // stores + log-softmax partials: thread t -> (n = t>>1, v-half q = t&1)
    const int n = tid >> 1, q = tid & 1;
    const int v0 = bm * 32 + q * 16;
    float4 vals[4];
    float m_loc = -1e30f;
#pragma unroll
    for (int k = 0; k < 4; ++k) {
        float4 cv = *(const float4*)(cs + n * 36 + q * 16 + 4 * k);
        float4 bv = *(const float4*)(h2ob + v0 + 4 * k);
        cv.x += bv.x; cv.y += bv.y; cv.z += bv.z; cv.w += bv.w;
        vals[k] = cv;
        *(float4*)(dlogits + (size_t)n * V + v0 + 4 * k) = cv;
        m_loc = fmaxf(m_loc, fmaxf(fmaxf(cv.x, cv.y), fmaxf(cv.z, cv.w)));
    }
    float s_loc = 0.f;
#pragma unroll
    for (int k = 0; k < 4; ++k) {
        s_loc += __expf(vals[k].x - m_loc) + __expf(vals[k].y - m_loc)
               + __expf(vals[k].z - m_loc) + __expf(vals[k].w - m_loc);
    }
    float m2 = fmaxf(m_loc, __shfl_xor(m_loc, 1, 64));
    s_loc *= __expf(m_loc - m2);
    float s2 = s_loc + __shfl_xor(s_loc, 1, 64);
    if (q == 0) {
        pmax[(size_t)n * VT + bm] = m2;
        psum[(size_t)n * VT + bm] = s2;
    }
}

// ---------------------------------------------------------------------------
// K4b: combine per-block partials -> lse[n]. grid 64, block 256.
// ---------------------------------------------------------------------------
__global__ __launch_bounds__(256) void k_lse(
    const float* __restrict__ pmax, const float* __restrict__ psum,
    float* __restrict__ lse)
{
    __shared__ float rm[4], rs[4];
    const int n = blockIdx.x, t = threadIdx.x;
    float pm[4], ps[4];
#pragma unroll
    for (int k = 0; k < 4; ++k) {
        int idx = t + 256 * k;
        pm[k] = (idx < VT) ? pmax[(size_t)n * VT + idx] : -1e30f;
        ps[k] = (idx < VT) ? psum[(size_t)n * VT + idx] : 0.f;
    }
    float mm = fmaxf(fmaxf(pm[0], pm[1]), fmaxf(pm[2], pm[3]));
#pragma unroll
    for (int off = 32; off > 0; off >>= 1) mm = fmaxf(mm, __shfl_xor(mm, off, 64));
    if ((t & 63) == 0) rm[t >> 6] = mm;
    __syncthreads();
    float m = fmaxf(fmaxf(rm[0], rm[1]), fmaxf(rm[2], rm[3]));

    float s = 0.f;
#pragma unroll
    for (int k = 0; k < 4; ++k) s += ps[k] * __expf(pm[k] - m);
#pragma unroll
    for (int off = 32; off > 0; off >>= 1) s += __shfl_xor(s, off, 64);
    if ((t & 63) == 0) rs[t >> 6] = s;
    __syncthreads();
    if (t == 0) {
        float st = rs[0] + rs[1] + rs[2] + rs[3];
        lse[n] = m + __logf(st);
    }
}

// ---------------------------------------------------------------------------
// K4c: normalize logits in place. grid (32, 64), block 256, float4.
// ---------------------------------------------------------------------------
__global__ __launch_bounds__(256) void k_norm(
    float* __restrict__ dlogits, const float* __restrict__ lse)
{
    const int n = blockIdx.y;
    const int t4 = blockIdx.x * 256 + threadIdx.x;   // float4 index in row
    if (t4 >= V / 4) return;
    float s = lse[n];
    float4* p = (float4*)(dlogits + (size_t)n * V) + t4;
    float4 v = *p;
    v.x -= s; v.y -= s; v.z -= s; v.w -= s;
    *p = v;
}

// ---------------------------------------------------------------------------
extern "C" void kernel_launch(void* const* d_in, const int* in_sizes, int n_in,
                              void* d_out, int out_size, void* d_ws, size_t ws_size,
                              hipStream_t stream)
{
    const int* ids   = (const int*)d_in[0];
    const float* h   = (const float*)d_in[1];
    const float* c   = (const float*)d_in[2];
    const float* enc = (const float*)d_in[3];
    const unsigned char* mask = (const unsigned char*)d_in[4];
    const float* embW = (const float*)d_in[5];
    const float* w_ih = (const float*)d_in[6];
    const float* b_ih = (const float*)d_in[7];
    const float* w_hh = (const float*)d_in[8];
    const float* b_hh = (const float*)d_in[9];
    const float* Wh   = (const float*)d_in[10];
    const float* Ws   = (const float*)d_in[11];
    const float* av   = (const float*)d_in[12];
    const float* h2oW = (const float*)d_in[13];
    const float* h2ob = (const float*)d_in[14];

    float* out = (float*)d_out;
    float* ws = (float*)d_ws;
    // layout (float offsets):
    float* gates_p = ws;                               // 1,048,576
    float* sproj   = ws + 1048576;                     // 32,768
    float* scorep  = ws + 1048576 + 32768;             // 65,536
    unsigned short* xb   = (unsigned short*)(ws + 1146880);  // 64x1024 bf16 (32,768 f)
    unsigned short* encb = (unsigned short*)(ws + 1179648);  // N*L*H bf16 (2,097,152 f)
    unsigned short* Wsb  = (unsigned short*)(ws + 3276800);  // H*H bf16 (131,072 f)
    // pmax/psum/lse overlay gates_p (dead after k_lstm_pw)
    float* pmax = ws;                                  // 64*VT = 64,000
    float* psum = ws + 64000;                          // 64,000
    float* lse  = ws + 128000;                         // 64

    k_prep<<<2176, 256, 0, stream>>>(enc, Ws, encb, Wsb);
    k_gates<<<dim3(32, 8), 256, 0, stream>>>(ids, h, embW, w_ih, w_hh, gates_p);
    k_lstm_pw<<<128, 256, 0, stream>>>(gates_p, b_ih, b_hh, c, out, xb);
    k_sproj<<<128, 256, 0, stream>>>(out, Wh, sproj);
    k_score_gemm<<<dim3(128, 8), 256, 0, stream>>>(encb, Wsb, sproj, av, scorep);
    k_softmax_ctx<<<64, 512, 0, stream>>>(scorep, mask, encb, xb);
    k_logits<<<VT, 128, 0, stream>>>(h2oW, xb, h2ob, out, pmax, psum);
    k_lse<<<64, 256, 0, stream>>>(pmax, psum, lse);
    k_norm<<<dim3(32, 64), 256, 0, stream>>>(out, lse);
}